// Round 1
// baseline (47.316 us; speedup 1.0000x reference)
//
#include <hip/hip_runtime.h>

// x[n] = 0.95 * x[n-1] + e[n], 64 rows x 480000 fp32, row-major.
// Single-pass block-local scan: each block handles a 4096-element tile of one
// row. Incoming state is approximated by a geometric-weighted reduction over
// the preceding 512 elements (0.95^512 ~ 4e-12 -> exact to fp32 purposes).

#define ROW_N   480000
#define TILE    4096
#define WARM    512
#define NTILES  ((ROW_N + TILE - 1) / TILE)   // 118
#define NROWS   64

__global__ __launch_bounds__(1024)
void deemph_kernel(const float* __restrict__ in, float* __restrict__ out) {
    const int row      = blockIdx.y;
    const int startcol = blockIdx.x * TILE;
    const int tid      = threadIdx.x;
    const int lane     = tid & 63;
    const int wave     = tid >> 6;

    const float* __restrict__ rin  = in  + (size_t)row * ROW_N;
    float*       __restrict__ rout = out + (size_t)row * ROW_N;

    __shared__ float warr[16];   // per-wave inclusive scan carries
    __shared__ float wsum[16];   // per-wave warm-up partial sums

    const float LOG2C = -0.07400058144377693f;  // log2(0.95)

    // ---- warm-up: carry_warm ~= x[startcol-1] = sum_m c^(m-1) e[start-m] ----
    float wpart = 0.0f;
    if (tid < WARM) {
        int col = startcol - WARM + tid;
        if (col >= 0) {
            // element e[start - 512 + tid], weight c^(511 - tid)
            float w = exp2f((float)(WARM - 1 - tid) * LOG2C);
            wpart = w * rin[col];
        }
    }
    #pragma unroll
    for (int d = 1; d < 64; d <<= 1)
        wpart += __shfl_xor(wpart, d, 64);

    // ---- main segment: 4 consecutive elements per thread (one float4) ----
    const int col   = startcol + tid * 4;
    const bool valid = (col < ROW_N);          // ROW_N % 4 == 0 -> all-or-nothing
    float e0 = 0.f, e1 = 0.f, e2 = 0.f, e3 = 0.f;
    if (valid) {
        float4 v = *reinterpret_cast<const float4*>(rin + col);
        e0 = v.x; e1 = v.y; e2 = v.z; e3 = v.w;
    }
    // local scan with zero initial state
    float l0 = e0;
    float l1 = fmaf(0.95f, l0, e1);
    float l2 = fmaf(0.95f, l1, e2);
    float l3 = fmaf(0.95f, l2, e3);

    // ---- wave64 inclusive scan of thread carries, multiplier c^4 per hop ----
    // M[s] = 0.95^(4 * 2^s)
    const float M0 = 0.81450625f;     // c^4
    const float M1 = 0.66342043f;     // c^8
    const float M2 = 0.44012667f;     // c^16
    const float M3 = 0.19371148f;     // c^32
    const float M4 = 0.03752413f;     // c^64
    const float M5 = 0.00140806f;     // c^128
    float b = l3;
    { float t = __shfl_up(b, 1,  64); if (lane >= 1)  b = fmaf(M0, t, b); }
    { float t = __shfl_up(b, 2,  64); if (lane >= 2)  b = fmaf(M1, t, b); }
    { float t = __shfl_up(b, 4,  64); if (lane >= 4)  b = fmaf(M2, t, b); }
    { float t = __shfl_up(b, 8,  64); if (lane >= 8)  b = fmaf(M3, t, b); }
    { float t = __shfl_up(b, 16, 64); if (lane >= 16) b = fmaf(M4, t, b); }
    { float t = __shfl_up(b, 32, 64); if (lane >= 32) b = fmaf(M5, t, b); }

    float excl = __shfl_up(b, 1, 64);
    if (lane == 0) excl = 0.0f;

    if (lane == 63) warr[wave] = b;
    if (lane == 0)  wsum[wave] = wpart;
    __syncthreads();

    // ---- cross-wave fold (16 waves, hop multiplier c^256) ----
    const float C256 = 1.9826347e-06f;   // 0.95^256
    float E = 0.0f;
    for (int u = 0; u < wave; ++u) E = fmaf(E, C256, warr[u]);
    float carry_warm = 0.0f;
    #pragma unroll
    for (int u = 0; u < 16; ++u) carry_warm += wsum[u];

    // state at wave start, then at this thread's segment start
    float pw = exp2f((float)(256 * wave) * LOG2C);   // c^(256*wave), underflows to 0 safely
    float Sw = fmaf(pw, carry_warm, E);
    float pl = exp2f((float)(4 * lane) * LOG2C);     // c^(4*lane)
    float Q  = fmaf(pl, Sw, excl);                   // exact state before this segment

    if (valid) {
        float4 r;
        r.x = fmaf(0.95f,       Q, l0);
        r.y = fmaf(0.9025f,     Q, l1);
        r.z = fmaf(0.857375f,   Q, l2);
        r.w = fmaf(0.81450625f, Q, l3);
        *reinterpret_cast<float4*>(rout + col) = r;
    }
}

extern "C" void kernel_launch(void* const* d_in, const int* in_sizes, int n_in,
                              void* d_out, int out_size, void* d_ws, size_t ws_size,
                              hipStream_t stream) {
    const float* in = (const float*)d_in[0];
    float* out = (float*)d_out;
    dim3 grid(NTILES, NROWS);
    deemph_kernel<<<grid, 1024, 0, stream>>>(in, out);
}